// Round 16
// baseline (408.170 us; speedup 1.0000x reference)
//
#include <hip/hip_runtime.h>
#include <hip/hip_bf16.h>
#include <math.h>

#define H 256
#define EPSV 1e-6f

typedef __attribute__((ext_vector_type(8))) short bf16x8;
typedef __attribute__((ext_vector_type(4))) float f32x4;
typedef __attribute__((ext_vector_type(4))) unsigned int uint4v;

// packed RNE f32x2 -> bf16x2 (compiles to v_cvt_pk_bf16_f32)
static __device__ __forceinline__ unsigned pkrn(float lo, float hi){
  __hip_bfloat162 h = __float22bfloat162_rn(make_float2(lo, hi));
  return *reinterpret_cast<unsigned*>(&h);
}
static __device__ __forceinline__ unsigned short f2bf(float x){
  union { float f; unsigned u; } v; v.f = x;
  unsigned r = v.u + 0x7FFF + ((v.u >> 16) & 1);
  return (unsigned short)(r >> 16);
}

// ---------- fused: edge-count histogram + W1 conversion (independent work) ----------
// perm(b) = b ^ (((b>>7)&3)<<4) bakes the LDS bank swizzle (rule #21).
__global__ void count_and_w1(const int* __restrict__ cidx, int* __restrict__ counts, int E,
                             int nCountBlk, const float* __restrict__ W1,
                             unsigned short* __restrict__ w1t2s){
  int b = blockIdx.x;
  if (b < nCountBlk){
    int e = b * 256 + threadIdx.x;
    if (e < E) atomicAdd(&counts[cidx[e]], 1);
  } else {
    int t = (b - nCountBlk) * 256 + threadIdx.x;   // 0 .. 262143
    int k = t >> 8, n = t & 255;
    int kg = k >> 5, klo = k & 31;
    unsigned bb = (unsigned)((n & 63) * 64 + klo * 2);
    bb ^= ((bb >> 7) & 3u) << 4;
    size_t byteaddr = (size_t)kg * 16384 + (size_t)(n >> 6) * 4096 + bb;
    w1t2s[byteaddr >> 1] = f2bf(W1[t]);
  }
}

__global__ __launch_bounds__(1024) void scan_offsets(const int* __restrict__ counts,
                                                     int* __restrict__ offsets, int n){
  __shared__ int a[1024];
  int tid = threadIdx.x;
  int per = (n + 1023) >> 10;
  int start = tid * per;
  int end = min(start + per, n);
  int s = 0;
  for (int i = start; i < end; ++i) s += counts[i];
  a[tid] = s;
  __syncthreads();
  for (int d = 1; d < 1024; d <<= 1){
    int v = 0;
    if (tid >= d) v = a[tid - d];
    __syncthreads();
    if (tid >= d) a[tid] += v;
    __syncthreads();
  }
  int run = a[tid] - s;
  for (int i = start; i < end; ++i){ offsets[i] = run; run += counts[i]; }
  if (tid == 1023) offsets[n] = a[1023];
}

__global__ void fill_kernel(const int* __restrict__ cidx, int* __restrict__ cursor,
                            const int* __restrict__ offs, int* __restrict__ elist, int E){
  int e = blockIdx.x * blockDim.x + threadIdx.x;
  if (e < E){
    int c = cidx[e];
    int pos = atomicAdd(&cursor[c], 1);
    elist[offs[c] + pos] = e;
  }
}

// ---------- per-case: sort edge list (deterministic) + deg + weighted sum ----------
__global__ __launch_bounds__(64) void case_sums(const float* __restrict__ er,
                                                const float* __restrict__ ew,
                                                int* __restrict__ elist,
                                                const int* __restrict__ offs,
                                                float* __restrict__ csum,
                                                float* __restrict__ cdeg){
  int c = blockIdx.x, lane = threadIdx.x;
  int s = offs[c], e = offs[c + 1];
  int n = e - s;
  __shared__ int vals[128], svals[128];

  bool lds_path = (n <= 128);
  if (lds_path && n > 1){
    int v0 = (lane < n)      ? elist[s + lane]      : 0x7fffffff;
    int v1 = (64 + lane < n) ? elist[s + 64 + lane] : 0x7fffffff;
    vals[lane] = v0; vals[64 + lane] = v1;
    __syncthreads();
    int r0 = 0, r1 = 0;
    for (int j = 0; j < n; ++j){
      int vj = vals[j];
      r0 += (vj < v0); r1 += (vj < v1);
    }
    if (lane < n)      svals[r0] = v0;
    if (64 + lane < n) svals[r1] = v1;
    __syncthreads();
    if (lane < n)      elist[s + lane]      = svals[lane];
    if (64 + lane < n) elist[s + 64 + lane] = svals[64 + lane];
  } else if (lds_path && n == 1){
    if (lane == 0) svals[0] = elist[s];
    __syncthreads();
  } else {
    if (lane == 0){
      for (int i = s + 1; i < e; ++i){
        int v = elist[i];
        int j = i - 1;
        while (j >= s && elist[j] > v){ elist[j + 1] = elist[j]; --j; }
        elist[j + 1] = v;
      }
    }
    __syncthreads();
  }

  f32x4 acc = (f32x4){0.f,0.f,0.f,0.f};
  float dacc = 0.f;
  if (lds_path){
    int i = 0;
    for (; i + 3 < n; i += 4){
      int e1 = svals[i], e2 = svals[i+1], e3 = svals[i+2], e4 = svals[i+3];
      float w1 = ew[e1], w2 = ew[e2], w3 = ew[e3], w4 = ew[e4];
      f32x4 v1 = *(const f32x4*)&er[(size_t)e1 * H + lane * 4];
      f32x4 v2 = *(const f32x4*)&er[(size_t)e2 * H + lane * 4];
      f32x4 v3 = *(const f32x4*)&er[(size_t)e3 * H + lane * 4];
      f32x4 v4 = *(const f32x4*)&er[(size_t)e4 * H + lane * 4];
      acc += v1 * w1; acc += v2 * w2; acc += v3 * w3; acc += v4 * w4;
      dacc += w1; dacc += w2; dacc += w3; dacc += w4;
    }
    for (; i < n; ++i){
      int e1 = svals[i];
      float w1 = ew[e1];
      acc += (*(const f32x4*)&er[(size_t)e1 * H + lane * 4]) * w1;
      dacc += w1;
    }
  } else {
    for (int i = 0; i < n; ++i){
      int e1 = elist[s + i];
      float w1 = ew[e1];
      acc += (*(const f32x4*)&er[(size_t)e1 * H + lane * 4]) * w1;
      dacc += w1;
    }
  }
  *(f32x4*)&csum[(size_t)c * H + lane * 4] = acc;
  if (lane == 0) cdeg[c] = dacc;
}

// ---------- fused feat-build + MLP (bf16 MFMA) -> logits ----------
// BM=64, 256 threads (4 waves, 1M x 4N, wave tile 64x64, acc[4][4]).
// K-EIGHTHS: feat LDS 16 KB; B staged via global_load_lds (2x16KB dbuf,
// per-wave-private 4KB quarters). Counted vmcnt (T3/T4), never 0 mid-loop.
// R16: T5 s_setprio(1) around each MFMA cluster -- the 3 co-resident blocks
// are phase-skewed (PACK vs CLUSTER), the role-diversity regime where
// setprio pays (m191-style), unlike lockstep GEMM (m190 null).
__global__ __launch_bounds__(256, 2) void fused_mlp(
    const float* __restrict__ er, const float* __restrict__ ew,
    const int* __restrict__ cidx, const float* __restrict__ cdeg,
    const float* __restrict__ csum, const unsigned short* __restrict__ w1t2s,
    const float* __restrict__ b1, const float* __restrict__ w2,
    const float* __restrict__ b2, float* __restrict__ logits, int E)
{
  __shared__ __align__(16) unsigned short featl[4 * 2048];  // 16 KB
  __shared__ __align__(16) unsigned short Bst[2 * 8192];    // 32 KB
  __shared__ float lpart[4][64];                            // 1 KB
  int tid = threadIdx.x;
  long e0 = (long)blockIdx.x * 64;

  int wn = tid >> 6, lane = tid & 63;          // 4 waves = 4 N-stripes
  int l15 = lane & 15, lg = lane >> 4;

  // ---- per-row parameters: 4 threads/row, 8 k-elems per thread per eighth ----
  int r = tid >> 2, q = tid & 3;
  long e = e0 + r;
  bool valid = (e < (long)E);
  long ec = valid ? e : 0;
  int   cce = cidx[ec];
  float w   = valid ? ew[ec] : 0.f;
  float deg = valid ? cdeg[cce] : 1.f;
  float rem = deg - w;
  bool  fb  = (rem <= EPSV);
  float inv  = fb ? (1.0f / fmaxf(deg, EPSV)) : (1.0f / fmaxf(rem, 1e-8f));
  float wsel = fb ? 0.f : w;
  const float* erow = er   + (size_t)ec  * H + q * 8;
  const float* srow = csum + (size_t)cce * H + q * 8;
  unsigned packoff = (unsigned)r * 32u + ((unsigned)(q ^ ((r >> 1) & 3))) * 8u;

  f32x4 acc[4][4];
  #pragma unroll
  for (int mt = 0; mt < 4; ++mt)
    #pragma unroll
    for (int nt = 0; nt < 4; ++nt) acc[mt][nt] = (f32x4){0.f,0.f,0.f,0.f};

  f32x4 xr[2], sr[2];

#define LOADQ(HH)                                                          \
  if (valid){                                                              \
    xr[0] = *(const f32x4*)(erow + (HH) * 32);                             \
    xr[1] = *(const f32x4*)(erow + (HH) * 32 + 4);                         \
    sr[0] = *(const f32x4*)(srow + (HH) * 32);                             \
    sr[1] = *(const f32x4*)(srow + (HH) * 32 + 4);                         \
  } else {                                                                 \
    xr[0] = (f32x4){0,0,0,0}; xr[1] = (f32x4){0,0,0,0};                    \
    sr[0] = (f32x4){0,0,0,0}; sr[1] = (f32x4){0,0,0,0};                    \
  }

// stage 4 KB (this wave's quarter) of kg-block KG into buffer BUF (4 async ops)
#define STAGE(BUF, KG)                                                     \
  { const char* gb_ = (const char*)w1t2s + ((size_t)(KG) * 16384 +         \
                      (size_t)wn * 4096 + (size_t)lane * 16);              \
    char* lb_ = (char*)Bst + ((BUF) * 16384 + wn * 4096 + lane * 16);      \
    __builtin_amdgcn_global_load_lds((const __attribute__((address_space(1))) void*)gb_,            (__attribute__((address_space(3))) void*)lb_,            16, 0, 0); \
    __builtin_amdgcn_global_load_lds((const __attribute__((address_space(1))) void*)(gb_ + 1024),   (__attribute__((address_space(3))) void*)(lb_ + 1024),   16, 0, 0); \
    __builtin_amdgcn_global_load_lds((const __attribute__((address_space(1))) void*)(gb_ + 2048),   (__attribute__((address_space(3))) void*)(lb_ + 2048),   16, 0, 0); \
    __builtin_amdgcn_global_load_lds((const __attribute__((address_space(1))) void*)(gb_ + 3072),   (__attribute__((address_space(3))) void*)(lb_ + 3072),   16, 0, 0); }

// cluster SG: 16 MFMA from featl[SG] x Bst[BUF]; T5 setprio around the MFMA body
#define CLUSTER(SG, BUF)                                                   \
  { bf16x8 bfr[4];                                                         \
    _Pragma("unroll")                                                      \
    for (int nt = 0; nt < 4; ++nt){                                        \
      unsigned lcol_ = (unsigned)(nt * 16 + l15);                          \
      unsigned by_ = (BUF) * 16384u + (unsigned)wn * 4096u + lcol_ * 64u   \
                   + (((unsigned)lg ^ ((lcol_ >> 1) & 3u)) * 16u);         \
      bfr[nt] = *(const bf16x8*)((const char*)Bst + by_);                  \
    }                                                                      \
    __builtin_amdgcn_s_setprio(1);                                         \
    _Pragma("unroll")                                                      \
    for (int mt = 0; mt < 4; ++mt){                                        \
      unsigned rr_ = (unsigned)(mt * 16 + l15);                            \
      unsigned le_ = ((unsigned)lg ^ ((rr_ >> 1) & 3u)) * 8u;              \
      bf16x8 afr = *(const bf16x8*)&featl[(SG) * 2048u + rr_ * 32u + le_]; \
      _Pragma("unroll")                                                    \
      for (int nt = 0; nt < 4; ++nt)                                       \
        acc[mt][nt] = __builtin_amdgcn_mfma_f32_16x16x32_bf16(afr, bfr[nt], acc[mt][nt], 0, 0, 0); \
    }                                                                      \
    __builtin_amdgcn_s_setprio(0);                                         \
  }

  // prologue: stage first two B-tiles (kg 0 and 8), load first A-quarter
  STAGE(0, 0)
  STAGE(1, 8)
  LOADQ(0)

  #pragma unroll 1
  for (int h = 0; h < 8; ++h){
    int hn = (h + 1) & 7;
    // ---- PACK eighth h: 4 segments x 64 rows x 32 k into featl ----
    {
      unsigned xw[4], cw[4], pw[4], dw[4];
      #pragma unroll
      for (int d = 0; d < 4; ++d){
        float x0 = xr[d >> 1][(d & 1) * 2 + 0], x1 = xr[d >> 1][(d & 1) * 2 + 1];
        float s0 = sr[d >> 1][(d & 1) * 2 + 0], s1 = sr[d >> 1][(d & 1) * 2 + 1];
        float c0 = (s0 - wsel * x0) * inv;
        float c1 = (s1 - wsel * x1) * inv;
        xw[d] = pkrn(x0, x1);
        cw[d] = pkrn(c0, c1);
        pw[d] = pkrn(x0 * c0, x1 * c1);
        dw[d] = pkrn(fabsf(x0 - c0), fabsf(x1 - c1));
      }
      *(uint4v*)&featl[0 * 2048 + packoff] = (uint4v){xw[0], xw[1], xw[2], xw[3]};
      *(uint4v*)&featl[1 * 2048 + packoff] = (uint4v){cw[0], cw[1], cw[2], cw[3]};
      *(uint4v*)&featl[2 * 2048 + packoff] = (uint4v){pw[0], pw[1], pw[2], pw[3]};
      *(uint4v*)&featl[3 * 2048 + packoff] = (uint4v){dw[0], dw[1], dw[2], dw[3]};
    }
    __syncthreads();   // feat ready; drains prev-iter stages -> C0/C1 wait-free

    CLUSTER(0, 0)                                        // kg = h
    asm volatile("s_waitcnt lgkmcnt(0)" ::: "memory");
    STAGE(0, 16 + h)                                     // for C2  -> queue [S16x4]
    CLUSTER(1, 1)                                        // kg = 8 + h
    asm volatile("s_waitcnt lgkmcnt(0)" ::: "memory");
    STAGE(1, 24 + h)                                     // for C3  -> [S16,S24]
    LOADQ(hn)                                            // -> [S16x4,S24x4,LQx8]=16
    asm volatile("s_waitcnt vmcnt(12)" ::: "memory");    // drain S16 ONLY (C2's dep)
    CLUSTER(2, 0)
    asm volatile("s_waitcnt lgkmcnt(0)" ::: "memory");
    STAGE(0, hn)                                         // -> [S24x4,LQx8,Shnx4]=16
    asm volatile("s_waitcnt vmcnt(12)" ::: "memory");    // drain S24 ONLY (C3's dep)
    CLUSTER(3, 1)
    asm volatile("s_waitcnt lgkmcnt(0)" ::: "memory");
    STAGE(1, 8 + hn)                                     // next iter C1
    __syncthreads();   // drains LOADQ + the two early stages (~500cy cover)
  }
  // keep tail LOADQ live (prevent DCE that would skew vmcnt counts)
  asm volatile("" :: "v"(xr[0][0]), "v"(xr[1][0]), "v"(sr[0][0]), "v"(sr[1][0]));
#undef LOADQ
#undef STAGE
#undef CLUSTER

  // ---- epilogue: relu(h+b1) dot W2 over this wave's 64 cols ----
  float p[4][4];
  #pragma unroll
  for (int mt = 0; mt < 4; ++mt)
    #pragma unroll
    for (int j = 0; j < 4; ++j) p[mt][j] = 0.f;

  #pragma unroll
  for (int nt = 0; nt < 4; ++nt){
    int col = wn * 64 + nt * 16 + l15;
    float b1c = b1[col], w2c = w2[col];
    #pragma unroll
    for (int mt = 0; mt < 4; ++mt)
      #pragma unroll
      for (int j = 0; j < 4; ++j)
        p[mt][j] += fmaxf(acc[mt][nt][j] + b1c, 0.f) * w2c;
  }
  #pragma unroll
  for (int mask = 1; mask < 16; mask <<= 1)
    #pragma unroll
    for (int mt = 0; mt < 4; ++mt)
      #pragma unroll
      for (int j = 0; j < 4; ++j)
        p[mt][j] += __shfl_xor(p[mt][j], mask);

  if (l15 == 0){
    #pragma unroll
    for (int mt = 0; mt < 4; ++mt)
      #pragma unroll
      for (int j = 0; j < 4; ++j)
        lpart[wn][mt * 16 + lg * 4 + j] = p[mt][j];
  }
  __syncthreads();
  if (tid < 64 && e0 + tid < (long)E)
    logits[e0 + tid] = lpart[0][tid] + lpart[1][tid] + lpart[2][tid] + lpart[3][tid] + b2[0];
}

// ---------- per-case softmax + final weighted aggregation: 1 wave per case ----------
__global__ __launch_bounds__(64) void finalize(
    const float* __restrict__ er, const float* __restrict__ ew,
    const float* __restrict__ logits, const int* __restrict__ elist,
    const int* __restrict__ offs, const float* __restrict__ cdeg,
    float* __restrict__ out)
{
  int c = blockIdx.x, lane = threadIdx.x;
  int s = offs[c], e = offs[c + 1];
  int n = e - s;
  if (n == 0){
    *(f32x4*)&out[(size_t)c * H + lane * 4] = (f32x4){0.f,0.f,0.f,0.f};
    return;
  }

  float m = -INFINITY;
  for (int i = lane; i < n; i += 64) m = fmaxf(m, logits[elist[s + i]]);
  #pragma unroll
  for (int mask = 32; mask > 0; mask >>= 1) m = fmaxf(m, __shfl_xor(m, mask));

  float sm = 0.f;
  for (int i = lane; i < n; i += 64) sm += expf(logits[elist[s + i]] - m);
  #pragma unroll
  for (int mask = 32; mask > 0; mask >>= 1) sm += __shfl_xor(sm, mask);

  float gsum = sm + 1e-8f;
  float degc = cdeg[c] + 1e-8f;

  __shared__ float fa[256];
  f32x4 acc = (f32x4){0.f,0.f,0.f,0.f};
  for (int base = 0; base < n; base += 256){
    int chunk = min(n - base, 256);
    for (int i = lane; i < chunk; i += 64){
      int ed = elist[s + base + i];
      fa[i] = 0.8f * expf(logits[ed] - m) / gsum + 0.2f * ew[ed] / degc;
    }
    __syncthreads();
    int i = 0;
    for (; i + 3 < chunk; i += 4){
      int ed0 = elist[s + base + i],     ed1 = elist[s + base + i + 1];
      int ed2 = elist[s + base + i + 2], ed3 = elist[s + base + i + 3];
      f32x4 v0 = *(const f32x4*)&er[(size_t)ed0 * H + lane * 4];
      f32x4 v1 = *(const f32x4*)&er[(size_t)ed1 * H + lane * 4];
      f32x4 v2 = *(const f32x4*)&er[(size_t)ed2 * H + lane * 4];
      f32x4 v3 = *(const f32x4*)&er[(size_t)ed3 * H + lane * 4];
      acc += fa[i] * v0;
      acc += fa[i + 1] * v1;
      acc += fa[i + 2] * v2;
      acc += fa[i + 3] * v3;
    }
    for (; i < chunk; ++i){
      int ed0 = elist[s + base + i];
      acc += fa[i] * (*(const f32x4*)&er[(size_t)ed0 * H + lane * 4]);
    }
    __syncthreads();
  }
  *(f32x4*)&out[(size_t)c * H + lane * 4] = acc;
}

extern "C" void kernel_launch(void* const* d_in, const int* in_sizes, int n_in,
                              void* d_out, int out_size, void* d_ws, size_t ws_size,
                              hipStream_t stream){
  const float* er  = (const float*)d_in[0];
  const float* ew  = (const float*)d_in[1];
  const int*   cid = (const int*)d_in[2];
  const float* W1  = (const float*)d_in[4];
  const float* b1  = (const float*)d_in[5];
  const float* W2  = (const float*)d_in[6];
  const float* b2  = (const float*)d_in[7];
  float* out = (float*)d_out;

  int E  = in_sizes[1];
  int NC = out_size / H;

  char* ws = (char*)d_ws;
  auto al = [](size_t x){ return (x + 255) & ~(size_t)255; };
  size_t o = 0;
  int* counts = (int*)(ws + o);  o = al(o + (size_t)NC * 4);
  int* cursor = (int*)(ws + o);  o = al(o + (size_t)NC * 4);
  int* offs   = (int*)(ws + o);  o = al(o + (size_t)(NC + 1) * 4);
  int* elist  = (int*)(ws + o);  o = al(o + (size_t)E * 4);
  float* cdeg = (float*)(ws + o); o = al(o + (size_t)NC * 4);
  float* csum = (float*)(ws + o); o = al(o + (size_t)NC * H * 4);
  float* logits = (float*)(ws + o); o = al(o + (size_t)E * 4);
  unsigned short* w1t2s = (unsigned short*)(ws + o); o = al(o + (size_t)1024 * H * 2);

  hipMemsetAsync(counts, 0, (size_t)NC * 4, stream);
  hipMemsetAsync(cursor, 0, (size_t)NC * 4, stream);

  int nCountBlk = (E + 255) / 256;
  count_and_w1<<<nCountBlk + 1024, 256, 0, stream>>>(cid, counts, E, nCountBlk, W1, w1t2s);
  scan_offsets<<<1, 1024, 0, stream>>>(counts, offs, NC);
  fill_kernel<<<(E + 255) / 256, 256, 0, stream>>>(cid, cursor, offs, elist, E);
  case_sums<<<NC, 64, 0, stream>>>(er, ew, elist, offs, csum, cdeg);
  fused_mlp<<<(E + 63) / 64, 256, 0, stream>>>(er, ew, cid, cdeg, csum, w1t2s, b1, W2, b2, logits, E);
  finalize<<<NC, 64, 0, stream>>>(er, ew, logits, elist, offs, cdeg, out);
}

// Round 17
// 401.872 us; speedup vs baseline: 1.0157x; 1.0157x over previous
//
#include <hip/hip_runtime.h>
#include <hip/hip_bf16.h>
#include <math.h>

#define H 256
#define EPSV 1e-6f

typedef __attribute__((ext_vector_type(8))) short bf16x8;
typedef __attribute__((ext_vector_type(4))) float f32x4;
typedef __attribute__((ext_vector_type(4))) unsigned int uint4v;

// packed RNE f32x2 -> bf16x2 (compiles to v_cvt_pk_bf16_f32)
static __device__ __forceinline__ unsigned pkrn(float lo, float hi){
  __hip_bfloat162 h = __float22bfloat162_rn(make_float2(lo, hi));
  return *reinterpret_cast<unsigned*>(&h);
}
static __device__ __forceinline__ unsigned short f2bf(float x){
  union { float f; unsigned u; } v; v.f = x;
  unsigned r = v.u + 0x7FFF + ((v.u >> 16) & 1);
  return (unsigned short)(r >> 16);
}

// ---------- counting sort by case ----------
__global__ void count_kernel(const int* __restrict__ cidx, int* __restrict__ counts, int E){
  int e = blockIdx.x * blockDim.x + threadIdx.x;
  if (e < E) atomicAdd(&counts[cidx[e]], 1);
}

__global__ __launch_bounds__(1024) void scan_offsets(const int* __restrict__ counts,
                                                     int* __restrict__ offsets, int n){
  __shared__ int a[1024];
  int tid = threadIdx.x;
  int per = (n + 1023) >> 10;
  int start = tid * per;
  int end = min(start + per, n);
  int s = 0;
  for (int i = start; i < end; ++i) s += counts[i];
  a[tid] = s;
  __syncthreads();
  for (int d = 1; d < 1024; d <<= 1){
    int v = 0;
    if (tid >= d) v = a[tid - d];
    __syncthreads();
    if (tid >= d) a[tid] += v;
    __syncthreads();
  }
  int run = a[tid] - s;
  for (int i = start; i < end; ++i){ offsets[i] = run; run += counts[i]; }
  if (tid == 1023) offsets[n] = a[1023];
}

__global__ void fill_kernel(const int* __restrict__ cidx, int* __restrict__ cursor,
                            const int* __restrict__ offs, int* __restrict__ elist, int E){
  int e = blockIdx.x * blockDim.x + threadIdx.x;
  if (e < E){
    int c = cidx[e];
    int pos = atomicAdd(&cursor[c], 1);
    elist[offs[c] + pos] = e;
  }
}

// ---------- W1 (1024x256 f32 row=k,col=n) -> staged-B layout ----------
// perm(b) = b ^ (((b>>7)&3)<<4) bakes the LDS bank swizzle (rule #21).
__global__ void w1_convert(const float* __restrict__ W1, unsigned short* __restrict__ w1t2s){
  int t = blockIdx.x * blockDim.x + threadIdx.x;
  int k = t >> 8, n = t & 255;
  int kg = k >> 5, klo = k & 31;
  unsigned b = (unsigned)((n & 63) * 64 + klo * 2);
  b ^= ((b >> 7) & 3u) << 4;
  size_t byteaddr = (size_t)kg * 16384 + (size_t)(n >> 6) * 4096 + b;
  w1t2s[byteaddr >> 1] = f2bf(W1[t]);
}

// ---------- per-case: sort edge list (deterministic) + deg + weighted sum ----------
__global__ __launch_bounds__(64) void case_sums(const float* __restrict__ er,
                                                const float* __restrict__ ew,
                                                int* __restrict__ elist,
                                                const int* __restrict__ offs,
                                                float* __restrict__ csum,
                                                float* __restrict__ cdeg){
  int c = blockIdx.x, lane = threadIdx.x;
  int s = offs[c], e = offs[c + 1];
  int n = e - s;
  __shared__ int vals[128], svals[128];

  bool lds_path = (n <= 128);
  if (lds_path && n > 1){
    int v0 = (lane < n)      ? elist[s + lane]      : 0x7fffffff;
    int v1 = (64 + lane < n) ? elist[s + 64 + lane] : 0x7fffffff;
    vals[lane] = v0; vals[64 + lane] = v1;
    __syncthreads();
    int r0 = 0, r1 = 0;
    for (int j = 0; j < n; ++j){
      int vj = vals[j];
      r0 += (vj < v0); r1 += (vj < v1);
    }
    if (lane < n)      svals[r0] = v0;
    if (64 + lane < n) svals[r1] = v1;
    __syncthreads();
    if (lane < n)      elist[s + lane]      = svals[lane];
    if (64 + lane < n) elist[s + 64 + lane] = svals[64 + lane];
  } else if (lds_path && n == 1){
    if (lane == 0) svals[0] = elist[s];
    __syncthreads();
  } else {
    if (lane == 0){
      for (int i = s + 1; i < e; ++i){
        int v = elist[i];
        int j = i - 1;
        while (j >= s && elist[j] > v){ elist[j + 1] = elist[j]; --j; }
        elist[j + 1] = v;
      }
    }
    __syncthreads();
  }

  f32x4 acc = (f32x4){0.f,0.f,0.f,0.f};
  float dacc = 0.f;
  if (lds_path){
    int i = 0;
    for (; i + 3 < n; i += 4){
      int e1 = svals[i], e2 = svals[i+1], e3 = svals[i+2], e4 = svals[i+3];
      float w1 = ew[e1], w2 = ew[e2], w3 = ew[e3], w4 = ew[e4];
      f32x4 v1 = *(const f32x4*)&er[(size_t)e1 * H + lane * 4];
      f32x4 v2 = *(const f32x4*)&er[(size_t)e2 * H + lane * 4];
      f32x4 v3 = *(const f32x4*)&er[(size_t)e3 * H + lane * 4];
      f32x4 v4 = *(const f32x4*)&er[(size_t)e4 * H + lane * 4];
      acc += v1 * w1; acc += v2 * w2; acc += v3 * w3; acc += v4 * w4;
      dacc += w1; dacc += w2; dacc += w3; dacc += w4;
    }
    for (; i < n; ++i){
      int e1 = svals[i];
      float w1 = ew[e1];
      acc += (*(const f32x4*)&er[(size_t)e1 * H + lane * 4]) * w1;
      dacc += w1;
    }
  } else {
    for (int i = 0; i < n; ++i){
      int e1 = elist[s + i];
      float w1 = ew[e1];
      acc += (*(const f32x4*)&er[(size_t)e1 * H + lane * 4]) * w1;
      dacc += w1;
    }
  }
  *(f32x4*)&csum[(size_t)c * H + lane * 4] = acc;
  if (lane == 0) cdeg[c] = dacc;
}

// ---------- fused feat-build + MLP (bf16 MFMA) -> logits ----------
// BM=64, 256 threads (4 waves, 1M x 4N, wave tile 64x64, acc[4][4]).
// K-EIGHTHS: feat LDS 16 KB; B staged via global_load_lds (2x16KB dbuf,
// per-wave-private 4KB quarters). Counted vmcnt (T3/T4), never 0 mid-loop.
// R17: setprio reverted (R16 A/B: -10us, starves co-resident blocks' staging).
__global__ __launch_bounds__(256, 2) void fused_mlp(
    const float* __restrict__ er, const float* __restrict__ ew,
    const int* __restrict__ cidx, const float* __restrict__ cdeg,
    const float* __restrict__ csum, const unsigned short* __restrict__ w1t2s,
    const float* __restrict__ b1, const float* __restrict__ w2,
    const float* __restrict__ b2, float* __restrict__ logits, int E)
{
  __shared__ __align__(16) unsigned short featl[4 * 2048];  // 16 KB
  __shared__ __align__(16) unsigned short Bst[2 * 8192];    // 32 KB
  __shared__ float lpart[4][64];                            // 1 KB
  int tid = threadIdx.x;
  long e0 = (long)blockIdx.x * 64;

  int wn = tid >> 6, lane = tid & 63;          // 4 waves = 4 N-stripes
  int l15 = lane & 15, lg = lane >> 4;

  // ---- per-row parameters: 4 threads/row, 8 k-elems per thread per eighth ----
  int r = tid >> 2, q = tid & 3;
  long e = e0 + r;
  bool valid = (e < (long)E);
  long ec = valid ? e : 0;
  int   cce = cidx[ec];
  float w   = valid ? ew[ec] : 0.f;
  float deg = valid ? cdeg[cce] : 1.f;
  float rem = deg - w;
  bool  fb  = (rem <= EPSV);
  float inv  = fb ? (1.0f / fmaxf(deg, EPSV)) : (1.0f / fmaxf(rem, 1e-8f));
  float wsel = fb ? 0.f : w;
  const float* erow = er   + (size_t)ec  * H + q * 8;
  const float* srow = csum + (size_t)cce * H + q * 8;
  unsigned packoff = (unsigned)r * 32u + ((unsigned)(q ^ ((r >> 1) & 3))) * 8u;

  f32x4 acc[4][4];
  #pragma unroll
  for (int mt = 0; mt < 4; ++mt)
    #pragma unroll
    for (int nt = 0; nt < 4; ++nt) acc[mt][nt] = (f32x4){0.f,0.f,0.f,0.f};

  f32x4 xr[2], sr[2];

#define LOADQ(HH)                                                          \
  if (valid){                                                              \
    xr[0] = *(const f32x4*)(erow + (HH) * 32);                             \
    xr[1] = *(const f32x4*)(erow + (HH) * 32 + 4);                         \
    sr[0] = *(const f32x4*)(srow + (HH) * 32);                             \
    sr[1] = *(const f32x4*)(srow + (HH) * 32 + 4);                         \
  } else {                                                                 \
    xr[0] = (f32x4){0,0,0,0}; xr[1] = (f32x4){0,0,0,0};                    \
    sr[0] = (f32x4){0,0,0,0}; sr[1] = (f32x4){0,0,0,0};                    \
  }

// stage 4 KB (this wave's quarter) of kg-block KG into buffer BUF (4 async ops)
#define STAGE(BUF, KG)                                                     \
  { const char* gb_ = (const char*)w1t2s + ((size_t)(KG) * 16384 +         \
                      (size_t)wn * 4096 + (size_t)lane * 16);              \
    char* lb_ = (char*)Bst + ((BUF) * 16384 + wn * 4096 + lane * 16);      \
    __builtin_amdgcn_global_load_lds((const __attribute__((address_space(1))) void*)gb_,            (__attribute__((address_space(3))) void*)lb_,            16, 0, 0); \
    __builtin_amdgcn_global_load_lds((const __attribute__((address_space(1))) void*)(gb_ + 1024),   (__attribute__((address_space(3))) void*)(lb_ + 1024),   16, 0, 0); \
    __builtin_amdgcn_global_load_lds((const __attribute__((address_space(1))) void*)(gb_ + 2048),   (__attribute__((address_space(3))) void*)(lb_ + 2048),   16, 0, 0); \
    __builtin_amdgcn_global_load_lds((const __attribute__((address_space(1))) void*)(gb_ + 3072),   (__attribute__((address_space(3))) void*)(lb_ + 3072),   16, 0, 0); }

// cluster SG: 16 MFMA from featl[SG] x Bst[BUF] (both swizzle-matched reads)
#define CLUSTER(SG, BUF)                                                   \
  { bf16x8 bfr[4];                                                         \
    _Pragma("unroll")                                                      \
    for (int nt = 0; nt < 4; ++nt){                                        \
      unsigned lcol_ = (unsigned)(nt * 16 + l15);                          \
      unsigned by_ = (BUF) * 16384u + (unsigned)wn * 4096u + lcol_ * 64u   \
                   + (((unsigned)lg ^ ((lcol_ >> 1) & 3u)) * 16u);         \
      bfr[nt] = *(const bf16x8*)((const char*)Bst + by_);                  \
    }                                                                      \
    _Pragma("unroll")                                                      \
    for (int mt = 0; mt < 4; ++mt){                                        \
      unsigned rr_ = (unsigned)(mt * 16 + l15);                            \
      unsigned le_ = ((unsigned)lg ^ ((rr_ >> 1) & 3u)) * 8u;              \
      bf16x8 afr = *(const bf16x8*)&featl[(SG) * 2048u + rr_ * 32u + le_]; \
      _Pragma("unroll")                                                    \
      for (int nt = 0; nt < 4; ++nt)                                       \
        acc[mt][nt] = __builtin_amdgcn_mfma_f32_16x16x32_bf16(afr, bfr[nt], acc[mt][nt], 0, 0, 0); \
    }                                                                      \
  }

  // prologue: stage first two B-tiles (kg 0 and 8), load first A-quarter
  STAGE(0, 0)
  STAGE(1, 8)
  LOADQ(0)

  #pragma unroll 1
  for (int h = 0; h < 8; ++h){
    int hn = (h + 1) & 7;
    // ---- PACK eighth h: 4 segments x 64 rows x 32 k into featl ----
    {
      unsigned xw[4], cw[4], pw[4], dw[4];
      #pragma unroll
      for (int d = 0; d < 4; ++d){
        float x0 = xr[d >> 1][(d & 1) * 2 + 0], x1 = xr[d >> 1][(d & 1) * 2 + 1];
        float s0 = sr[d >> 1][(d & 1) * 2 + 0], s1 = sr[d >> 1][(d & 1) * 2 + 1];
        float c0 = (s0 - wsel * x0) * inv;
        float c1 = (s1 - wsel * x1) * inv;
        xw[d] = pkrn(x0, x1);
        cw[d] = pkrn(c0, c1);
        pw[d] = pkrn(x0 * c0, x1 * c1);
        dw[d] = pkrn(fabsf(x0 - c0), fabsf(x1 - c1));
      }
      *(uint4v*)&featl[0 * 2048 + packoff] = (uint4v){xw[0], xw[1], xw[2], xw[3]};
      *(uint4v*)&featl[1 * 2048 + packoff] = (uint4v){cw[0], cw[1], cw[2], cw[3]};
      *(uint4v*)&featl[2 * 2048 + packoff] = (uint4v){pw[0], pw[1], pw[2], pw[3]};
      *(uint4v*)&featl[3 * 2048 + packoff] = (uint4v){dw[0], dw[1], dw[2], dw[3]};
    }
    __syncthreads();   // feat ready; drains prev-iter stages -> C0/C1 wait-free

    CLUSTER(0, 0)                                        // kg = h
    asm volatile("s_waitcnt lgkmcnt(0)" ::: "memory");
    STAGE(0, 16 + h)                                     // for C2  -> queue [S16x4]
    CLUSTER(1, 1)                                        // kg = 8 + h
    asm volatile("s_waitcnt lgkmcnt(0)" ::: "memory");
    STAGE(1, 24 + h)                                     // for C3  -> [S16,S24]
    LOADQ(hn)                                            // -> [S16x4,S24x4,LQx8]=16
    asm volatile("s_waitcnt vmcnt(12)" ::: "memory");    // drain S16 ONLY (C2's dep)
    CLUSTER(2, 0)
    asm volatile("s_waitcnt lgkmcnt(0)" ::: "memory");
    STAGE(0, hn)                                         // -> [S24x4,LQx8,Shnx4]=16
    asm volatile("s_waitcnt vmcnt(12)" ::: "memory");    // drain S24 ONLY (C3's dep)
    CLUSTER(3, 1)
    asm volatile("s_waitcnt lgkmcnt(0)" ::: "memory");
    STAGE(1, 8 + hn)                                     // next iter C1
    __syncthreads();   // drains LOADQ + the two early stages (~500cy cover)
  }
  // keep tail LOADQ live (prevent DCE that would skew vmcnt counts)
  asm volatile("" :: "v"(xr[0][0]), "v"(xr[1][0]), "v"(sr[0][0]), "v"(sr[1][0]));
#undef LOADQ
#undef STAGE
#undef CLUSTER

  // ---- epilogue: relu(h+b1) dot W2 over this wave's 64 cols ----
  float p[4][4];
  #pragma unroll
  for (int mt = 0; mt < 4; ++mt)
    #pragma unroll
    for (int j = 0; j < 4; ++j) p[mt][j] = 0.f;

  #pragma unroll
  for (int nt = 0; nt < 4; ++nt){
    int col = wn * 64 + nt * 16 + l15;
    float b1c = b1[col], w2c = w2[col];
    #pragma unroll
    for (int mt = 0; mt < 4; ++mt)
      #pragma unroll
      for (int j = 0; j < 4; ++j)
        p[mt][j] += fmaxf(acc[mt][nt][j] + b1c, 0.f) * w2c;
  }
  #pragma unroll
  for (int mask = 1; mask < 16; mask <<= 1)
    #pragma unroll
    for (int mt = 0; mt < 4; ++mt)
      #pragma unroll
      for (int j = 0; j < 4; ++j)
        p[mt][j] += __shfl_xor(p[mt][j], mask);

  if (l15 == 0){
    #pragma unroll
    for (int mt = 0; mt < 4; ++mt)
      #pragma unroll
      for (int j = 0; j < 4; ++j)
        lpart[wn][mt * 16 + lg * 4 + j] = p[mt][j];
  }
  __syncthreads();
  if (tid < 64 && e0 + tid < (long)E)
    logits[e0 + tid] = lpart[0][tid] + lpart[1][tid] + lpart[2][tid] + lpart[3][tid] + b2[0];
}

// ---------- per-case softmax + final weighted aggregation ----------
// R17: 2 independent waves per block, one case each; NO LDS, NO barriers.
// fa recomputed inline per lane (logits/ew loads are wave-uniform -> scalar
// broadcast; the redundant exp is ~n VALU ops per case, negligible).
__global__ __launch_bounds__(128) void finalize(
    const float* __restrict__ er, const float* __restrict__ ew,
    const float* __restrict__ logits, const int* __restrict__ elist,
    const int* __restrict__ offs, const float* __restrict__ cdeg,
    float* __restrict__ out, int NC)
{
  int c = blockIdx.x * 2 + (threadIdx.x >> 6);
  if (c >= NC) return;
  int lane = threadIdx.x & 63;
  int s = offs[c], e = offs[c + 1];
  int n = e - s;
  if (n == 0){
    *(f32x4*)&out[(size_t)c * H + lane * 4] = (f32x4){0.f,0.f,0.f,0.f};
    return;
  }

  float m = -INFINITY;
  for (int i = lane; i < n; i += 64) m = fmaxf(m, logits[elist[s + i]]);
  #pragma unroll
  for (int mask = 32; mask > 0; mask >>= 1) m = fmaxf(m, __shfl_xor(m, mask));

  float sm = 0.f;
  for (int i = lane; i < n; i += 64) sm += expf(logits[elist[s + i]] - m);
  #pragma unroll
  for (int mask = 32; mask > 0; mask >>= 1) sm += __shfl_xor(sm, mask);

  float ginv = 0.8f / (sm + 1e-8f);
  float dinv = 0.2f / (cdeg[c] + 1e-8f);

  f32x4 acc = (f32x4){0.f,0.f,0.f,0.f};
  int i = 0;
  for (; i + 3 < n; i += 4){
    int ed0 = elist[s + i],     ed1 = elist[s + i + 1];
    int ed2 = elist[s + i + 2], ed3 = elist[s + i + 3];
    float fa0 = expf(logits[ed0] - m) * ginv + ew[ed0] * dinv;
    float fa1 = expf(logits[ed1] - m) * ginv + ew[ed1] * dinv;
    float fa2 = expf(logits[ed2] - m) * ginv + ew[ed2] * dinv;
    float fa3 = expf(logits[ed3] - m) * ginv + ew[ed3] * dinv;
    f32x4 v0 = *(const f32x4*)&er[(size_t)ed0 * H + lane * 4];
    f32x4 v1 = *(const f32x4*)&er[(size_t)ed1 * H + lane * 4];
    f32x4 v2 = *(const f32x4*)&er[(size_t)ed2 * H + lane * 4];
    f32x4 v3 = *(const f32x4*)&er[(size_t)ed3 * H + lane * 4];
    acc += fa0 * v0;
    acc += fa1 * v1;
    acc += fa2 * v2;
    acc += fa3 * v3;
  }
  for (; i < n; ++i){
    int ed0 = elist[s + i];
    float fa0 = expf(logits[ed0] - m) * ginv + ew[ed0] * dinv;
    acc += fa0 * (*(const f32x4*)&er[(size_t)ed0 * H + lane * 4]);
  }
  *(f32x4*)&out[(size_t)c * H + lane * 4] = acc;
}

extern "C" void kernel_launch(void* const* d_in, const int* in_sizes, int n_in,
                              void* d_out, int out_size, void* d_ws, size_t ws_size,
                              hipStream_t stream){
  const float* er  = (const float*)d_in[0];
  const float* ew  = (const float*)d_in[1];
  const int*   cid = (const int*)d_in[2];
  const float* W1  = (const float*)d_in[4];
  const float* b1  = (const float*)d_in[5];
  const float* W2  = (const float*)d_in[6];
  const float* b2  = (const float*)d_in[7];
  float* out = (float*)d_out;

  int E  = in_sizes[1];
  int NC = out_size / H;

  char* ws = (char*)d_ws;
  auto al = [](size_t x){ return (x + 255) & ~(size_t)255; };
  size_t o = 0;
  int* counts = (int*)(ws + o);  o = al(o + (size_t)NC * 4);
  int* cursor = (int*)(ws + o);  o = al(o + (size_t)NC * 4);
  int* offs   = (int*)(ws + o);  o = al(o + (size_t)(NC + 1) * 4);
  int* elist  = (int*)(ws + o);  o = al(o + (size_t)E * 4);
  float* cdeg = (float*)(ws + o); o = al(o + (size_t)NC * 4);
  float* csum = (float*)(ws + o); o = al(o + (size_t)NC * H * 4);
  float* logits = (float*)(ws + o); o = al(o + (size_t)E * 4);
  unsigned short* w1t2s = (unsigned short*)(ws + o); o = al(o + (size_t)1024 * H * 2);

  hipMemsetAsync(counts, 0, (size_t)NC * 4, stream);
  hipMemsetAsync(cursor, 0, (size_t)NC * 4, stream);

  count_kernel<<<(E + 255) / 256, 256, 0, stream>>>(cid, counts, E);
  w1_convert<<<(1024 * H) / 256, 256, 0, stream>>>(W1, w1t2s);
  scan_offsets<<<1, 1024, 0, stream>>>(counts, offs, NC);
  fill_kernel<<<(E + 255) / 256, 256, 0, stream>>>(cid, cursor, offs, elist, E);
  case_sums<<<NC, 64, 0, stream>>>(er, ew, elist, offs, csum, cdeg);
  fused_mlp<<<(E + 63) / 64, 256, 0, stream>>>(er, ew, cid, cdeg, csum, w1t2s, b1, W2, b2, logits, E);
  finalize<<<(NC + 1) / 2, 128, 0, stream>>>(er, ew, logits, elist, offs, cdeg, out, NC);
}